// Round 10
// baseline (143.373 us; speedup 1.0000x reference)
//
#include <hip/hip_runtime.h>
#include <cstddef>

constexpr int Bn = 16, Dn = 512, Nn = 4096, Kn = 64;
constexpr int PN = 128;            // panel n-size
constexpr int NP = Nn / PN;        // 32 panels per b
constexpr int Dp = 520;            // padded aggp pitch (non-pow2, 16B-aligned)
constexpr float FEPS = 1e-12f;

typedef __bf16 bf16x8 __attribute__((ext_vector_type(8)));
typedef float f32x4 __attribute__((ext_vector_type(4)));

__device__ __forceinline__ unsigned short bf_bits(__bf16 h) {
  union { __bf16 b; unsigned short u; } c;
  c.b = h;
  return c.u;
}

// ---------------------------------------------------------------------------
// kW: split conv_w[K][D] (row-major, d-contiguous) into bf16 hi/lo arrays.
// ---------------------------------------------------------------------------
__global__ __launch_bounds__(256) void kW(const float* __restrict__ w,
                                          unsigned short* __restrict__ w_hi,
                                          unsigned short* __restrict__ w_lo) {
  const int idx = blockIdx.x * 256 + threadIdx.x;  // 32768 total
  const float v = w[idx];
  const __bf16 h = (__bf16)v;          // RNE
  const float r = v - (float)h;
  const __bf16 l = (__bf16)r;
  w_hi[idx] = bf_bits(h);
  w_lo[idx] = bf_bits(l);
}

// ---------------------------------------------------------------------------
// kF v2: fused logits+softmax+agg. One block = one (b, 128-n panel),
// 512 threads = 8 waves -> grid 512 = 2 blocks/CU (two independent barrier
// domains per CU; that's the round-10 change).
// Phase 1 (validated math): 3-term bf16-split MFMA logits; x staged through
//   double-buffered LDS transpose (pitch 33); softmax in-register.
//   Wave wv owns 16-n subtile wv*16.
// Inter-phase: assign*invn bf16 hi/lo in LDS [ng16][k64][8].
// Phase 2 (validated math): agg partial; wave wv owns 64-d slice (4 tiles),
//   all 64 k; acc2[4][4]; B-frags straight from global (L2-hot), bf16-hi.
// Writes: aggp[b][p][64][Dp] partials, massp[b][p][64].
// ---------------------------------------------------------------------------
__global__ __launch_bounds__(512, 4) void kF(const float* __restrict__ x,
                                             const unsigned short* __restrict__ w_hi,
                                             const unsigned short* __restrict__ w_lo,
                                             const float* __restrict__ conv_b,
                                             float* __restrict__ aggp,
                                             float* __restrict__ massp) {
  __shared__ float smem[2 * PN * 33];  // 33.8 KB xs dbuf; reused as assign
  __shared__ float msum[8][64];
  const int tid = threadIdx.x;
  const int l = tid & 63;
  const int wv = tid >> 6;   // 0..7
  const int ll = l & 15;
  const int lg = l >> 4;
  const int b = blockIdx.x >> 5;
  const int p = blockIdx.x & 31;
  const int n0 = p << 7;
  const float* xb = x + (size_t)b * Dn * Nn + n0;

  // ===================== Phase 1: logits =====================
  f32x4 acc[4];
#pragma unroll
  for (int kt = 0; kt < 4; ++kt) acc[kt] = (f32x4){0.f, 0.f, 0.f, 0.f};
  float ss = 0.f;

  // staging role: row = tid>>4 (0..31), cols sc0..sc0+7
  const int srow = tid >> 4;
  const int sc0 = (tid & 15) << 3;
  float4 pf0 = *(const float4*)(xb + (size_t)srow * Nn + sc0);
  float4 pf1 = *(const float4*)(xb + (size_t)srow * Nn + sc0 + 4);

  for (int dc = 0; dc < Dn; dc += 32) {
    float* xs = smem + ((dc >> 5) & 1) * (PN * 33);
    xs[(sc0 + 0) * 33 + srow] = pf0.x;
    xs[(sc0 + 1) * 33 + srow] = pf0.y;
    xs[(sc0 + 2) * 33 + srow] = pf0.z;
    xs[(sc0 + 3) * 33 + srow] = pf0.w;
    xs[(sc0 + 4) * 33 + srow] = pf1.x;
    xs[(sc0 + 5) * 33 + srow] = pf1.y;
    xs[(sc0 + 6) * 33 + srow] = pf1.z;
    xs[(sc0 + 7) * 33 + srow] = pf1.w;
    if (dc + 32 < Dn) {
      pf0 = *(const float4*)(xb + (size_t)(dc + 32 + srow) * Nn + sc0);
      pf1 = *(const float4*)(xb + (size_t)(dc + 32 + srow) * Nn + sc0 + 4);
    }
    __syncthreads();  // xs(chunk) ready

    const int ncol = (wv << 4) + ll;
    const float* xcol = xs + ncol * 33 + lg * 8;
    float xv[8];
#pragma unroll
    for (int j = 0; j < 8; ++j) xv[j] = xcol[j];
    bf16x8 bh, bl;
#pragma unroll
    for (int j = 0; j < 8; ++j) {
      ss = fmaf(xv[j], xv[j], ss);
      const __bf16 h = (__bf16)xv[j];
      bh[j] = h;
      bl[j] = (__bf16)(xv[j] - (float)h);
    }
#pragma unroll
    for (int kt = 0; kt < 4; ++kt) {
      const size_t woff = (size_t)(kt * 16 + ll) * Dn + dc + lg * 8;
      bf16x8 ah = *(const bf16x8*)(w_hi + woff);
      bf16x8 al = *(const bf16x8*)(w_lo + woff);
      acc[kt] = __builtin_amdgcn_mfma_f32_16x16x32_bf16(ah, bh, acc[kt], 0, 0, 0);
      acc[kt] = __builtin_amdgcn_mfma_f32_16x16x32_bf16(ah, bl, acc[kt], 0, 0, 0);
      acc[kt] = __builtin_amdgcn_mfma_f32_16x16x32_bf16(al, bh, acc[kt], 0, 0, 0);
    }
  }

  // ---- softmax (in-register, per 16-n subtile) ----
  ss += __shfl_xor(ss, 16);
  ss += __shfl_xor(ss, 32);
  const float iv = 1.f / fmaxf(sqrtf(ss), FEPS);
  float lgt[16];
#pragma unroll
  for (int kt = 0; kt < 4; ++kt)
#pragma unroll
    for (int r = 0; r < 4; ++r)
      lgt[kt * 4 + r] = fmaf(acc[kt][r], iv, conv_b[kt * 16 + lg * 4 + r]);
  float pmax = lgt[0];
#pragma unroll
  for (int i = 1; i < 16; ++i) pmax = fmaxf(pmax, lgt[i]);
  pmax = fmaxf(pmax, __shfl_xor(pmax, 16));
  pmax = fmaxf(pmax, __shfl_xor(pmax, 32));
  float ex[16];
  float psum = 0.f;
#pragma unroll
  for (int i = 0; i < 16; ++i) {
    ex[i] = expf(lgt[i] - pmax);
    psum += ex[i];
  }
  psum += __shfl_xor(psum, 16);
  psum += __shfl_xor(psum, 32);
  const float isum = 1.f / psum;

  __syncthreads();  // all xs reads done before smem reused as assign

  // ---- assign hi/lo bf16 into LDS ([ng][k][8]) + mass partials ----
  unsigned short* as_hi = (unsigned short*)smem;          // 16 KB
  unsigned short* as_lo = as_hi + PN * Kn;                // 16 KB
  const int ngb = (wv << 1) + (ll >> 3);
  const int jj = ll & 7;
#pragma unroll
  for (int i = 0; i < 16; ++i) {
    const int k = (i >> 2) * 16 + lg * 4 + (i & 3);
    const float a = ex[i] * isum;
    const float v = a * iv;
    const __bf16 h = (__bf16)v;
    as_hi[(ngb * 64 + k) * 8 + jj] = bf_bits(h);
    as_lo[(ngb * 64 + k) * 8 + jj] = bf_bits((__bf16)(v - (float)h));
    float m = a;
    m += __shfl_xor(m, 1);
    m += __shfl_xor(m, 2);
    m += __shfl_xor(m, 4);
    m += __shfl_xor(m, 8);
    if (ll == 0) msum[wv][k] = m;
  }
  __syncthreads();  // assign + msum visible to all
  if (tid < 64) {
    float s = 0.f;
#pragma unroll
    for (int ww = 0; ww < 8; ++ww) s += msum[ww][tid];
    massp[((b << 5) + p) * Kn + tid] = s;
  }

  // ===================== Phase 2: agg partial =====================
  // wave wv -> d in [wv*64, wv*64+64); M=k, N=d, K=n(panel)
  f32x4 acc2[4][4];
#pragma unroll
  for (int kt = 0; kt < 4; ++kt)
#pragma unroll
    for (int dt = 0; dt < 4; ++dt) acc2[kt][dt] = (f32x4){0.f, 0.f, 0.f, 0.f};

  const float* xq = x + (size_t)b * Dn * Nn +
                    (size_t)(wv * 64 + ll) * Nn + n0 + lg * 8;

#pragma unroll
  for (int nc = 0; nc < PN; nc += 32) {
    const int ng = (nc >> 3) + lg;
    bf16x8 af_h[4], af_l[4];
#pragma unroll
    for (int kt = 0; kt < 4; ++kt) {
      const int idx = (ng * 64 + kt * 16 + ll) * 8;
      af_h[kt] = *(const bf16x8*)(as_hi + idx);
      af_l[kt] = *(const bf16x8*)(as_lo + idx);
    }
    bf16x8 bx[4];
#pragma unroll
    for (int dt = 0; dt < 4; ++dt) {
      const float* xr = xq + (size_t)(dt * 16) * Nn + nc;
      float4 x0 = *(const float4*)(xr);
      float4 x1 = *(const float4*)(xr + 4);
      bx[dt][0] = (__bf16)x0.x; bx[dt][1] = (__bf16)x0.y;
      bx[dt][2] = (__bf16)x0.z; bx[dt][3] = (__bf16)x0.w;
      bx[dt][4] = (__bf16)x1.x; bx[dt][5] = (__bf16)x1.y;
      bx[dt][6] = (__bf16)x1.z; bx[dt][7] = (__bf16)x1.w;
    }
#pragma unroll
    for (int kt = 0; kt < 4; ++kt)
#pragma unroll
      for (int dt = 0; dt < 4; ++dt) {
        acc2[kt][dt] = __builtin_amdgcn_mfma_f32_16x16x32_bf16(
            af_h[kt], bx[dt], acc2[kt][dt], 0, 0, 0);
        acc2[kt][dt] = __builtin_amdgcn_mfma_f32_16x16x32_bf16(
            af_l[kt], bx[dt], acc2[kt][dt], 0, 0, 0);
      }
  }

  // store partials: aggp[((b*32+p)*64 + k)*Dp + d]
  float* outb = aggp + (size_t)((b << 5) + p) * Kn * Dp;
#pragma unroll
  for (int kt = 0; kt < 4; ++kt)
#pragma unroll
    for (int dt = 0; dt < 4; ++dt) {
      const int krow = kt * 16 + (lg << 2);
      const int dcol = wv * 64 + dt * 16 + ll;
      float* op = outb + (size_t)krow * Dp + dcol;
#pragma unroll
      for (int r = 0; r < 4; ++r) op[(size_t)r * Dp] = acc2[kt][dt][r];
    }
}

// ---------------------------------------------------------------------------
// kC1: per (b,k): mass from massp (32 panels); vlad = sum(aggp over 32
// panels) - mass*c; intra-normalize over d.
// ---------------------------------------------------------------------------
__device__ __forceinline__ float blockReduceSum(float v, float* sb) {
#pragma unroll
  for (int off = 32; off > 0; off >>= 1) v += __shfl_down(v, off, 64);
  const int lane = threadIdx.x & 63, w = threadIdx.x >> 6;
  if (lane == 0) sb[w] = v;
  __syncthreads();
  if (threadIdx.x == 0) sb[4] = sb[0] + sb[1] + sb[2] + sb[3];
  __syncthreads();
  return sb[4];
}

__global__ __launch_bounds__(256) void kC1(const float* __restrict__ massp,
                                           const float* __restrict__ aggp,
                                           const float* __restrict__ centroids,
                                           float* __restrict__ out,
                                           float* __restrict__ rowsq) {
  __shared__ float sb[5];
  const int tid = threadIdx.x;
  const int b = blockIdx.x >> 6, k = blockIdx.x & 63;
  float s = 0.f;
  if (tid < 32) s = massp[((b << 5) + tid) * Kn + k];
  const float mass = blockReduceSum(s, sb);
  float v[2];
  float sq = 0.f;
#pragma unroll
  for (int u = 0; u < 2; ++u) {
    const int d = tid + (u << 8);
    float val = -mass * centroids[k * Dn + d];
#pragma unroll 8
    for (int pp = 0; pp < 32; ++pp)
      val += aggp[((size_t)((b << 5) + pp) * Kn + k) * Dp + d];
    v[u] = val;
    sq = fmaf(val, val, sq);
  }
  const float rsq = blockReduceSum(sq, sb);
  const float inv = 1.f / fmaxf(sqrtf(rsq), FEPS);
#pragma unroll
  for (int u = 0; u < 2; ++u)
    out[((size_t)b * Kn + k) * Dn + tid + (u << 8)] = v[u] * inv;
  if (tid == 0) rowsq[b * Kn + k] = rsq * inv * inv;
}

// ---------------------------------------------------------------------------
// kC2: final global L2 norm per batch.
// ---------------------------------------------------------------------------
__global__ __launch_bounds__(256) void kC2(float* __restrict__ out,
                                           const float* __restrict__ rowsq) {
  __shared__ float sg;
  const int b = blockIdx.x, tid = threadIdx.x;
  float v = (tid < 64) ? rowsq[b * Kn + tid] : 0.f;
  if (tid < 64) {
#pragma unroll
    for (int off = 32; off > 0; off >>= 1) v += __shfl_down(v, off, 64);
  }
  if (tid == 0) sg = 1.f / fmaxf(sqrtf(v), FEPS);
  __syncthreads();
  const float inv = sg;
  float* ob = out + (size_t)b * (Kn * Dn);
  for (int t = tid; t < Kn * Dn; t += 256) ob[t] *= inv;
}

// ---------------------------------------------------------------------------
extern "C" void kernel_launch(void* const* d_in, const int* in_sizes, int n_in,
                              void* d_out, int out_size, void* d_ws,
                              size_t ws_size, hipStream_t stream) {
  const float* x = (const float*)d_in[0];
  const float* centroids = (const float*)d_in[1];
  const float* conv_w = (const float*)d_in[2];
  const float* conv_b = (const float*)d_in[3];
  float* out = (float*)d_out;
  float* ws = (float*)d_ws;
  // ws layout (float units):
  //   aggp    [0,        17039360)  16 b x 32 p x 64 k x Dp(520) f32
  //   w_hi    [17039360, 17055744)  64x512 bf16 = 16384 floats
  //   w_lo    [17055744, 17072128)
  //   massp   [17072128, 17104896)  16 b x 32 p x 64 k
  //   rowsq   [17104896, 17105920)
  float* aggp = ws;
  unsigned short* w_hi = (unsigned short*)(ws + 17039360);
  unsigned short* w_lo = (unsigned short*)(ws + 17055744);
  float* massp = ws + 17072128;
  float* rowsq = ws + 17104896;

  kW<<<128, 256, 0, stream>>>(conv_w, w_hi, w_lo);
  kF<<<512, 512, 0, stream>>>(x, w_hi, w_lo, conv_b, aggp, massp);
  kC1<<<1024, 256, 0, stream>>>(massp, aggp, centroids, out, rowsq);
  kC2<<<16, 256, 0, stream>>>(out, rowsq);
}